// Round 5
// baseline (154.370 us; speedup 1.0000x reference)
//
#include <hip/hip_runtime.h>
#include <hip/hip_cooperative_groups.h>
#include <cfloat>
#include <climits>

namespace cg = cooperative_groups;

#define B 4
#define N 3000
#define C 21
#define SORT_N 256          // max candidates per (b,c); E[M]=142.9, sigma~11.7 -> 9.7 sigma margin
#define WORDS 4             // SORT_N / 64
#define GRID_BLOCKS (B * (C - 1))   // 80; also covers pointwise (80*256=20480 >= 12000 rows)

// Output layout (flat float32, reference return order):
//   [0,        B*N*4)   nms_reg_rounded
//   [B*N*4,    B*N*5)   nms_cls_sig
//   [B*N*5,    B*N*9)   boxes
//   [B*N*9,    B*N*30)  probs
//   [B*N*30,   B*N*31)  keep (0.0/1.0)
//
// keep ownership (each element written exactly once):
//   argmax==0 -> phase-1 thread writes keep=0
//   argmax==c -> NMS block (b,c) writes keep 0/1 (n==0 forced 0: reference's keep[0]-clobber)

__global__ __launch_bounds__(256) void fused_coop(
    const float* __restrict__ nms_reg,
    const float* __restrict__ nms_cls,
    const float* __restrict__ rcnn_reg,
    const float* __restrict__ rcnn_cls,
    const int* __restrict__ red_p,
    float* __restrict__ out,
    int2* __restrict__ cw)        // per-row (argmax, float_bits(p[argmax]))
{
    const int tid = threadIdx.x;

    float* out_round = out;               // B*N*4
    float* out_sig   = out + B * N * 4;   // B*N
    float* out_boxes = out + B * N * 5;   // B*N*4
    float* out_probs = out + B * N * 9;   // B*N*C
    float* out_keep  = out + B * N * 30;  // B*N

    // ================= phase 1: pointwise, one row per thread =================
    {
        const int bn = blockIdx.x * 256 + tid;
        if (bn < B * N) {
            float red = (float)(*red_p);

            float4 nr = ((const float4*)nms_reg)[bn];
            float r0 = floorf(__fmul_rn(nr.x, red)) / red;
            float r1 = floorf(__fmul_rn(nr.y, red)) / red;
            float r2 = ceilf (__fmul_rn(nr.z, red)) / red;
            float r3 = ceilf (__fmul_rn(nr.w, red)) / red;
            ((float4*)out_round)[bn] = make_float4(r0, r1, r2, r3);

            float4 rr = ((const float4*)rcnn_reg)[bn];
            ((float4*)out_boxes)[bn] = make_float4(__fadd_rn(rr.x, r0), __fadd_rn(rr.y, r1),
                                                   __fadd_rn(rr.z, r2), __fadd_rn(rr.w, r3));

            // stable sigmoid
            float x = nms_cls[bn];
            float s;
            if (x >= 0.0f) s = 1.0f / (1.0f + expf(-x));
            else { float e = expf(x); s = e / (1.0f + e); }
            out_sig[bn] = s;

            // softmax over C=21 (reference op order) + first-max argmax on probs
            const float* lg = rcnn_cls + (size_t)bn * C;
            float m = lg[0];
            #pragma unroll
            for (int c = 1; c < C; ++c) m = fmaxf(m, lg[c]);
            float p[C];
            float sum = 0.0f;
            #pragma unroll
            for (int c = 0; c < C; ++c) {
                p[c] = expf(__fsub_rn(lg[c], m));
                sum = __fadd_rn(sum, p[c]);
            }
            float* po = out_probs + (size_t)bn * C;
            float best = -1.0f; int am = 0;
            #pragma unroll
            for (int c = 0; c < C; ++c) {
                float pc = __fdiv_rn(p[c], sum);
                po[c] = pc;
                if (pc > best) { best = pc; am = c; }   // strict > = first max (jnp.argmax)
            }
            cw[bn] = make_int2(am, __float_as_int(best));
            if (am == 0) out_keep[bn] = 0.0f;           // background row: owned here
        }
    }

    cg::this_grid().sync();   // cooperative launch: ws + out_boxes now visible grid-wide

    // ================= phase 2: NMS, one block per (b, c) =================
    const int b = blockIdx.x / (C - 1);
    const int c = blockIdx.x % (C - 1) + 1;

    __shared__ int   gid[SORT_N];
    __shared__ float gsc[SORT_N];
    __shared__ int   sid[SORT_N];
    __shared__ float bt[SORT_N], bl[SORT_N], bb[SORT_N], br_[SORT_N], ar[SORT_N];
    __shared__ __align__(16) unsigned long long msk[SORT_N][WORDS];   // 8 KB
    __shared__ int mcount;

    if (tid == 0) mcount = 0;
    __syncthreads();

    // gather: coalesced 8B reads of precomputed (cls, score); LDS-atomic compaction
    for (int n = tid; n < N; n += 256) {
        int2 v = cw[b * N + n];
        if (v.x == c) {
            int pos = atomicAdd(&mcount, 1);
            if (pos < SORT_N) { gid[pos] = n; gsc[pos] = __int_as_float(v.y); }
        }
    }
    __syncthreads();
    const int M = min(mcount, SORT_N);

    // rank-sort: thread s (< M) computes its entry's rank under (score desc, idx asc)
    // -- total order (ids unique), deterministic regardless of gather order
    int   myid = 0; float mysc = 0.0f; float4 mybox; float mya = 0.0f; int rank = 0;
    if (tid < M) {
        myid = gid[tid]; mysc = gsc[tid];
        mybox = ((const float4*)out_boxes)[b * N + myid];   // L2-hot from phase 1
        mya = __fmul_rn(fmaxf(__fsub_rn(mybox.z, mybox.x), 0.0f),
                        fmaxf(__fsub_rn(mybox.w, mybox.y), 0.0f));
        for (int j = 0; j < M; ++j) {                       // LDS broadcast reads
            float sj = gsc[j]; int ij = gid[j];
            bool precede = (sj > mysc) || (sj == mysc && ij < myid);
            rank += precede ? 1 : 0;
        }
    }
    __syncthreads();
    if (tid < M) {
        sid[rank] = myid;
        bt[rank] = mybox.x; bl[rank] = mybox.y; bb[rank] = mybox.z; br_[rank] = mybox.w;
        ar[rank] = mya;
    }
    __syncthreads();

    // thread tid owns sorted column tid
    float myt = 0.0f, myl = 0.0f, myb = 0.0f, myr = 0.0f; mya = 0.0f;
    if (tid < M) { myt = bt[tid]; myl = bl[tid]; myb = bb[tid]; myr = br_[tid]; mya = ar[tid]; }

    // row masks via per-wave ballot: msk[r][w] bit k == (row r suppresses col w*64+k)
    for (int r = 0; r < M; ++r) {
        float rt = bt[r], rl = bl[r], rb = bb[r], rr = br_[r], ra = ar[r];  // LDS broadcast
        bool supp = false;
        if (tid > r && tid < M) {
            float ih = fmaxf(__fsub_rn(fminf(rb, myb), fmaxf(rt, myt)), 0.0f);
            float iw = fmaxf(__fsub_rn(fminf(rr, myr), fmaxf(rl, myl)), 0.0f);
            float inter = __fmul_rn(ih, iw);
            float uni = __fsub_rn(__fadd_rn(ra, mya), inter);
            float iou = __fdiv_rn(inter, fmaxf(uni, 1e-9f));
            supp = iou > 0.5f;
        }
        unsigned long long wmask = __ballot(supp);
        if ((tid & 63) == 0) msk[r][tid >> 6] = wmask;
    }
    __syncthreads();

    // serial greedy scan, redundant in every thread (registers + LDS mask reads)
    auto onesk = [](int k) -> unsigned long long {
        return k <= 0 ? 0ull : (k >= 64 ? ~0ull : ((1ull << k) - 1ull));
    };
    unsigned long long a0 = onesk(M), a1 = onesk(M - 64), a2 = onesk(M - 128), a3 = onesk(M - 192);

    {
        int e = min(64, M);
        #pragma unroll 4
        for (int i = 0; i < e; ++i) {
            unsigned long long sel = 0ull - ((a0 >> i) & 1ull);
            a0 &= ~(msk[i][0] & sel);
            a1 &= ~(msk[i][1] & sel);
            a2 &= ~(msk[i][2] & sel);
            a3 &= ~(msk[i][3] & sel);
        }
    }
    {
        int e = min(128, M);
        #pragma unroll 4
        for (int i = 64; i < e; ++i) {
            unsigned long long sel = 0ull - ((a1 >> (i - 64)) & 1ull);
            a1 &= ~(msk[i][1] & sel);
            a2 &= ~(msk[i][2] & sel);
            a3 &= ~(msk[i][3] & sel);
        }
    }
    {
        int e = min(192, M);
        #pragma unroll 4
        for (int i = 128; i < e; ++i) {
            unsigned long long sel = 0ull - ((a2 >> (i - 128)) & 1ull);
            a2 &= ~(msk[i][2] & sel);
            a3 &= ~(msk[i][3] & sel);
        }
    }
    {
        int e = min(256, M);
        #pragma unroll 4
        for (int i = 192; i < e; ++i) {
            unsigned long long sel = 0ull - ((a3 >> (i - 192)) & 1ull);
            a3 &= ~(msk[i][3] & sel);
        }
    }

    // write keep for all candidates of this (b,c); n==0 forced 0
    if (tid < M) {
        unsigned long long aw = (tid < 64) ? a0 : (tid < 128) ? a1 : (tid < 192) ? a2 : a3;
        bool kept = (aw >> (tid & 63)) & 1ull;
        int n = sid[tid];
        out_keep[b * N + n] = (kept && n != 0) ? 1.0f : 0.0f;
    }
}

extern "C" void kernel_launch(void* const* d_in, const int* in_sizes, int n_in,
                              void* d_out, int out_size, void* d_ws, size_t ws_size,
                              hipStream_t stream) {
    const float* nms_reg  = (const float*)d_in[0];
    const float* nms_cls  = (const float*)d_in[1];
    const float* rcnn_reg = (const float*)d_in[2];
    const float* rcnn_cls = (const float*)d_in[3];
    const int*   red_p    = (const int*)d_in[4];
    float* out = (float*)d_out;
    int2* cw = (int2*)d_ws;   // B*N int2 = 96 KiB

    void* args[] = { (void*)&nms_reg, (void*)&nms_cls, (void*)&rcnn_reg, (void*)&rcnn_cls,
                     (void*)&red_p, (void*)&out, (void*)&cw };
    hipLaunchCooperativeKernel((void*)fused_coop, dim3(GRID_BLOCKS), dim3(256), args, 0, stream);
}

// Round 6
// 111.674 us; speedup vs baseline: 1.3823x; 1.3823x over previous
//
#include <hip/hip_runtime.h>
#include <cfloat>
#include <climits>

#define B 4
#define N 3000
#define C 21
#define SORT_N 256          // max candidates per (b,c); E[M]=142.9, sigma~11.7 -> 9.7 sigma margin
#define WORDS 4             // SORT_N / 64
#define NMS_BLOCKS (B * (C - 1))   // 80
#define PW_BLOCKS 12               // 12 * 1024 = 12288 >= 12000 rows
#define TPB 1024

// Output layout (flat float32, reference return order):
//   [0,        B*N*4)   nms_reg_rounded
//   [B*N*4,    B*N*5)   nms_cls_sig
//   [B*N*5,    B*N*9)   boxes
//   [B*N*9,    B*N*30)  probs
//   [B*N*30,   B*N*31)  keep (0.0/1.0)
//
// keep ownership (each element written exactly once, no inter-block ordering):
//   argmax==0 -> pointwise block writes keep=0
//   argmax==c -> NMS block (b,c) writes keep 0/1 (n==0 forced 0: reference's keep[0]-clobber)

// Bit-identical in both paths: explicit rounding intrinsics, fixed op order.
__device__ __forceinline__ int softmax_am(const float* __restrict__ lg,
                                          float* __restrict__ pmax_out,
                                          float* __restrict__ pstore) {
    float m = lg[0];
    #pragma unroll
    for (int c = 1; c < C; ++c) m = fmaxf(m, lg[c]);
    float p[C];
    float sum = 0.0f;
    #pragma unroll
    for (int c = 0; c < C; ++c) {
        p[c] = expf(__fsub_rn(lg[c], m));
        sum = __fadd_rn(sum, p[c]);
    }
    float best = -1.0f; int bc = 0;
    #pragma unroll
    for (int c = 0; c < C; ++c) {
        float pc = __fdiv_rn(p[c], sum);
        if (pstore) pstore[c] = pc;
        if (pc > best) { best = pc; bc = c; }   // strict > = first max (jnp.argmax on probs)
    }
    *pmax_out = best;
    return bc;
}

__device__ __forceinline__ void make_boxes(float4 nr, float4 rr, float red,
                                           float4* rounded, float4* box) {
    float r0 = floorf(__fmul_rn(nr.x, red)) / red;
    float r1 = floorf(__fmul_rn(nr.y, red)) / red;
    float r2 = ceilf (__fmul_rn(nr.z, red)) / red;
    float r3 = ceilf (__fmul_rn(nr.w, red)) / red;
    *rounded = make_float4(r0, r1, r2, r3);
    *box = make_float4(__fadd_rn(rr.x, r0), __fadd_rn(rr.y, r1),
                       __fadd_rn(rr.z, r2), __fadd_rn(rr.w, r3));
}

__global__ __launch_bounds__(TPB) void fused_kernel(
    const float* __restrict__ nms_reg,
    const float* __restrict__ nms_cls,
    const float* __restrict__ rcnn_reg,
    const float* __restrict__ rcnn_cls,
    const int* __restrict__ red_p,
    float* __restrict__ out)
{
    const int tid = threadIdx.x;

    float* out_round = out;               // B*N*4
    float* out_sig   = out + B * N * 4;   // B*N
    float* out_boxes = out + B * N * 5;   // B*N*4
    float* out_probs = out + B * N * 9;   // B*N*C
    float* out_keep  = out + B * N * 30;  // B*N

    if (blockIdx.x >= NMS_BLOCKS) {
        // ---------------- pointwise path: one row per thread ----------------
        const int bn = (blockIdx.x - NMS_BLOCKS) * TPB + tid;
        if (bn >= B * N) return;

        float red = (float)(*red_p);

        float4 nr = ((const float4*)nms_reg)[bn];
        float4 rr = ((const float4*)rcnn_reg)[bn];
        float4 rounded, box;
        make_boxes(nr, rr, red, &rounded, &box);
        ((float4*)out_round)[bn] = rounded;
        ((float4*)out_boxes)[bn] = box;

        // stable sigmoid
        float x = nms_cls[bn];
        float s;
        if (x >= 0.0f) s = 1.0f / (1.0f + expf(-x));
        else { float e = expf(x); s = e / (1.0f + e); }
        out_sig[bn] = s;

        float pm;
        int am = softmax_am(rcnn_cls + (size_t)bn * C, &pm, out_probs + (size_t)bn * C);

        if (am == 0) out_keep[bn] = 0.0f;   // background row: owned here
        return;
    }

    // ---------------- NMS path: one block (1024 thr = 16 waves) per (b, c) ----------------
    const int b = blockIdx.x / (C - 1);
    const int c = blockIdx.x % (C - 1) + 1;
    const int lane = tid & 63;

    __shared__ int   gid[SORT_N];
    __shared__ float gsc[SORT_N];
    __shared__ int   rnk[SORT_N];
    __shared__ int   sid[SORT_N];
    __shared__ float bt[SORT_N], bl[SORT_N], bb[SORT_N], br_[SORT_N], ar[SORT_N];
    __shared__ __align__(16) unsigned long long msk[SORT_N][WORDS];   // 8 KB
    __shared__ int mcount;

    if (tid == 0) mcount = 0;
    if (tid < SORT_N) rnk[tid] = 0;
    __syncthreads();

    // ---- gather: 3 rows/thread, softmax once per row, per-wave ballot compaction ----
    #pragma unroll
    for (int chunk = 0; chunk < 3; ++chunk) {
        int n = chunk * TPB + tid;
        bool match = false;
        float pm = 0.0f;
        if (n < N) {
            int am = softmax_am(rcnn_cls + (size_t)(b * N + n) * C, &pm, nullptr);
            match = (am == c);
        }
        unsigned long long mb = __ballot(match);
        int base = 0;
        if (lane == 0 && mb) base = atomicAdd(&mcount, __popcll(mb));
        base = __shfl(base, 0);
        if (match) {
            int pos = base + __popcll(mb & ((1ull << lane) - 1ull));
            if (pos < SORT_N) { gid[pos] = n; gsc[pos] = pm; }
        }
    }
    __syncthreads();
    const int M = min(mcount, SORT_N);

    // ---- rank-sort: 4 threads per entry, 64 broadcast-compares each ----
    // order = (score desc, idx asc): total order (ids unique) -> deterministic
    {
        int e = tid & 255, q = tid >> 8;
        if (e < M) {
            float mys = gsc[e]; int myi = gid[e];
            int j0 = q * 64, j1 = min(j0 + 64, M);
            int partial = 0;
            for (int j = j0; j < j1; ++j) {
                float sj = gsc[j]; int ij = gid[j];
                partial += ((sj > mys) || (sj == mys && ij < myi)) ? 1 : 0;
            }
            if (partial) atomicAdd(&rnk[e], partial);
        }
    }
    __syncthreads();

    // ---- scatter into sorted order + compute boxes (bit-identical ops) ----
    if (tid < M) {
        float red = (float)(*red_p);
        int n = gid[tid];
        int rank = rnk[tid];
        float4 nr = ((const float4*)nms_reg)[b * N + n];
        float4 rr = ((const float4*)rcnn_reg)[b * N + n];
        float4 rounded, box;
        make_boxes(nr, rr, red, &rounded, &box);
        sid[rank] = n;
        bt[rank] = box.x; bl[rank] = box.y; bb[rank] = box.z; br_[rank] = box.w;
        ar[rank] = __fmul_rn(fmaxf(__fsub_rn(box.z, box.x), 0.0f),
                             fmaxf(__fsub_rn(box.w, box.y), 0.0f));
    }
    __syncthreads();

    // ---- mask build: wave-group g handles rows [g*64, g*64+64), ballot per wave ----
    // msk[r][w] bit k == (row r suppresses column j = w*64+k)
    {
        int g = tid >> 8;          // group 0..3 (4 waves each)
        int j = tid & 255;         // column this thread owns within its group
        int w = (tid >> 6) & 3;    // word index = which 64-column chunk this wave covers
        float jt = 0.f, jl = 0.f, jb = 0.f, jr = 0.f, ja = 0.f;
        if (j < M) { jt = bt[j]; jl = bl[j]; jb = bb[j]; jr = br_[j]; ja = ar[j]; }
        int r0 = g * 64, r1 = min(r0 + 64, M);
        for (int r = r0; r < r1; ++r) {
            float rt = bt[r], rl = bl[r], rb = bb[r], rr = br_[r], ra = ar[r];  // LDS broadcast
            bool supp = false;
            if (j > r && j < M) {
                float ih = fmaxf(__fsub_rn(fminf(rb, jb), fmaxf(rt, jt)), 0.0f);
                float iw = fmaxf(__fsub_rn(fminf(rr, jr), fmaxf(rl, jl)), 0.0f);
                float inter = __fmul_rn(ih, iw);
                float uni = __fsub_rn(__fadd_rn(ra, ja), inter);
                float iou = __fdiv_rn(inter, fmaxf(uni, 1e-9f));
                supp = iou > 0.5f;
            }
            unsigned long long wm = __ballot(supp);
            if (lane == 0) msk[r][w] = wm;
        }
    }
    __syncthreads();

    // ---- serial greedy scan, redundant per thread, registers + prefetchable LDS reads ----
    auto onesk = [](int k) -> unsigned long long {
        return k <= 0 ? 0ull : (k >= 64 ? ~0ull : ((1ull << k) - 1ull));
    };
    unsigned long long a0 = onesk(M), a1 = onesk(M - 64), a2 = onesk(M - 128), a3 = onesk(M - 192);

    {
        int e = min(64, M);
        #pragma unroll 4
        for (int i = 0; i < e; ++i) {
            unsigned long long sel = 0ull - ((a0 >> i) & 1ull);
            a0 &= ~(msk[i][0] & sel);
            a1 &= ~(msk[i][1] & sel);
            a2 &= ~(msk[i][2] & sel);
            a3 &= ~(msk[i][3] & sel);
        }
    }
    {
        int e = min(128, M);
        #pragma unroll 4
        for (int i = 64; i < e; ++i) {
            unsigned long long sel = 0ull - ((a1 >> (i - 64)) & 1ull);
            a1 &= ~(msk[i][1] & sel);
            a2 &= ~(msk[i][2] & sel);
            a3 &= ~(msk[i][3] & sel);
        }
    }
    {
        int e = min(192, M);
        #pragma unroll 4
        for (int i = 128; i < e; ++i) {
            unsigned long long sel = 0ull - ((a2 >> (i - 128)) & 1ull);
            a2 &= ~(msk[i][2] & sel);
            a3 &= ~(msk[i][3] & sel);
        }
    }
    {
        int e = min(256, M);
        #pragma unroll 4
        for (int i = 192; i < e; ++i) {
            unsigned long long sel = 0ull - ((a3 >> (i - 192)) & 1ull);
            a3 &= ~(msk[i][3] & sel);
        }
    }

    // ---- write keep for all candidates of this (b,c); n==0 forced 0 ----
    if (tid < M) {
        unsigned long long aw = (tid < 64) ? a0 : (tid < 128) ? a1 : (tid < 192) ? a2 : a3;
        bool kept = (aw >> (tid & 63)) & 1ull;
        int n = sid[tid];
        out_keep[b * N + n] = (kept && n != 0) ? 1.0f : 0.0f;
    }
}

extern "C" void kernel_launch(void* const* d_in, const int* in_sizes, int n_in,
                              void* d_out, int out_size, void* d_ws, size_t ws_size,
                              hipStream_t stream) {
    const float* nms_reg  = (const float*)d_in[0];
    const float* nms_cls  = (const float*)d_in[1];
    const float* rcnn_reg = (const float*)d_in[2];
    const float* rcnn_cls = (const float*)d_in[3];
    const int*   red_p    = (const int*)d_in[4];
    float* out = (float*)d_out;

    dim3 grid(NMS_BLOCKS + PW_BLOCKS);   // 80 NMS (long pole) + 12 pointwise, 1024 thr each
    fused_kernel<<<grid, TPB, 0, stream>>>(nms_reg, nms_cls, rcnn_reg, rcnn_cls, red_p, out);
}